// Round 13
// baseline (1061.283 us; speedup 1.0000x reference)
//
#include <hip/hip_runtime.h>
#include <math.h>

#define STEPS 19
#define THREADS 256
#define L2E 1.44269504088896340736f   // log2(e)

typedef _Float16 half8   __attribute__((ext_vector_type(8)));   // MFMA A/B frag
typedef float    floatx4 __attribute__((ext_vector_type(4)));   // MFMA C/D frag
typedef __fp16   half2_t __attribute__((ext_vector_type(2)));   // packed f16 pair

// Per-wave LDS region: A-staging uses first 4096 B (ONE 32-k half at a time,
// overwritten between MFMA halves); C-stage (5120 B, stride 20 dwords) overlays.
#define WAVE_LDS 5120

// d_ws byte offsets
#define WS_BH    0      // h-layer2 B-frags  [u][kk][lane]*16B = 4096
#define WS_BZ    4096   // z-layer2 B-frags (pre-scaled by -log2e) = 4096
#define WS_H1W0  8192   // 25 half2: {Wh1[0][2q],Wh1[0][2q+1]}
#define WS_H1W1  8292   // 25 half2: row 1
#define WS_H1B   8392   // 25 half2: bh1 pairs
#define WS_Z1W0  8492   // 25 half2: -L2E*Wz1 row 0 pairs
#define WS_Z1W1  8592   // 25 half2: -L2E*Wz1 row 1 pairs
#define WS_Z1B   8692   // 25 half2: -L2E*bz1 pairs
#define WS_WZ3   8792   // 40  f32: -L2E*Wz3
#define WS_BZ3   8952   // 2   f32: -L2E*bz3

#define LDS_FENCE() asm volatile("" ::: "memory")

__device__ __forceinline__ float lrelu(float x) { return fmaxf(x, 0.01f * x); }
__device__ __forceinline__ float sigm2(float y) {   // sigmoid, -log2e pre-folded
    return __builtin_amdgcn_rcpf(1.0f + __builtin_amdgcn_exp2f(y));
}
__device__ __forceinline__ unsigned int pkrtz_u(float a, float b) {
    return __builtin_bit_cast(unsigned int, __builtin_amdgcn_cvt_pkrtz(a, b));
}
__device__ __forceinline__ unsigned int packh2(float a, float b) {
    half2_t h; h.x = (__fp16)a; h.y = (__fp16)b;
    return __builtin_bit_cast(unsigned int, h);
}
__device__ __forceinline__ unsigned int h2bits(half2_t h) {
    return __builtin_bit_cast(unsigned int, h);
}
__device__ __forceinline__ half2_t bits2h(unsigned int u) {
    return __builtin_bit_cast(half2_t, u);
}

// packed-f16 sigmoid of a pre-scaled pair: y = -log2e*x; out = 1/(1+2^y)
__device__ __forceinline__ half2_t sigm_h2(half2_t y) {
#if __has_builtin(__builtin_elementwise_exp2) && __has_builtin(__builtin_amdgcn_rcph)
    half2_t e = __builtin_elementwise_exp2(y);            // 2x v_exp_f16
    e = e + (half2_t){(__fp16)1.0f, (__fp16)1.0f};        // v_pk_add_f16
    half2_t r;
    r.x = __builtin_amdgcn_rcph(e.x);                     // v_rcp_f16
    r.y = __builtin_amdgcn_rcph(e.y);
    return r;
#else
    return bits2h(pkrtz_u(sigm2((float)y.x), sigm2((float)y.y)));
#endif
}

// --- pack kernel ---
__global__ __launch_bounds__(256) void pack_kernel(
    const float* __restrict__ Wh1, const float* __restrict__ bh1,
    const float* __restrict__ Wh2, const float* __restrict__ bh2,
    const float* __restrict__ Wz1, const float* __restrict__ bz1,
    const float* __restrict__ Wz2, const float* __restrict__ bz2,
    const float* __restrict__ Wz3, const float* __restrict__ bz3,
    char* __restrict__ ws)
{
    const int t = threadIdx.x;
    // B-frags (16x16x32 f16): lane holds B[k=(lane>>4)*8+j][n=lane&15], j=0..7.
    // Bias row at k==50 (A supplies 1.0); k>50 rows ZERO (annihilate A pad).
    for (int e = t; e < 512; e += 256) {
        const int layer = e >> 8, r = e & 255;
        const int u = r >> 7, kk = (r >> 6) & 1, lane = r & 63;
        const int n = u * 16 + (lane & 15);
        const float* W2 = layer ? Wz2 : Wh2;
        const float* b2 = layer ? bz2 : bh2;
        const float scale = layer ? -L2E : 1.0f;
        unsigned int dw[4];
        #pragma unroll
        for (int d = 0; d < 4; ++d) {
            float v[2];
            #pragma unroll
            for (int h = 0; h < 2; ++h) {
                const int k = kk * 32 + ((lane >> 4) & 3) * 8 + 2 * d + h;
                float x = 0.0f;
                if (n < 20) {
                    if (k < 50)       x = W2[k * 20 + n] * scale;
                    else if (k == 50) x = b2[n] * scale;
                }
                v[h] = x;
            }
            dw[d] = packh2(v[0], v[1]);
        }
        *(uint4*)(ws + (layer ? WS_BZ : WS_BH) + (size_t)((u * 2 + kk) * 64 + lane) * 16)
            = make_uint4(dw[0], dw[1], dw[2], dw[3]);
    }
    if (t < 25) {
        ((unsigned int*)(ws + WS_H1W0))[t] = packh2(Wh1[2 * t],      Wh1[2 * t + 1]);
        ((unsigned int*)(ws + WS_H1W1))[t] = packh2(Wh1[50 + 2 * t], Wh1[51 + 2 * t]);
        ((unsigned int*)(ws + WS_H1B))[t]  = packh2(bh1[2 * t],      bh1[2 * t + 1]);
        ((unsigned int*)(ws + WS_Z1W0))[t] = packh2(-L2E * Wz1[2 * t],      -L2E * Wz1[2 * t + 1]);
        ((unsigned int*)(ws + WS_Z1W1))[t] = packh2(-L2E * Wz1[50 + 2 * t], -L2E * Wz1[51 + 2 * t]);
        ((unsigned int*)(ws + WS_Z1B))[t]  = packh2(-L2E * bz1[2 * t],      -L2E * bz1[2 * t + 1]);
    }
    if (t < 40)  ((float*)(ws + WS_WZ3))[t] = -L2E * Wz3[t];
    if (t < 2)   ((float*)(ws + WS_BZ3))[t] = -L2E * bz3[t];
}

__global__ __launch_bounds__(THREADS)
__attribute__((amdgpu_waves_per_eu(8)))   // pin RA <= 64 VGPR (r12 measured 60 with
                                          // MORE A-transients) -> 8 waves/EU possible;
                                          // LDS 20480/block -> 8 blocks/CU -> 32-wave cap
void recurrent_kernel(
    const float* __restrict__ w,
    const float* __restrict__ Wh3, const float* __restrict__ bh3,
    const char* __restrict__ ws,
    float* __restrict__ out, int nrows)
{
    __shared__ __align__(16) char lds[4 * WAVE_LDS];
    const int t    = threadIdx.x;
    const int lane = t & 63;
    const int wid  = t >> 6;
    const int lq   = (lane >> 4) & 3;
    const int ll   = lane & 15;
    char* ldsw = lds + wid * WAVE_LDS;

    // A-frag staging (ONE 32-k half at a time; conflict-free, r10-analyzed).
    char* awb = ldsw + (lane >> 4) * 1024 + (lane & 15) * 16;
    const char* arb = ldsw + lane * 16;
    // C-stage (overlays A region): row stride 20 dwords; u=1 invalid lanes wrap and
    // are overwritten by later u=0 writes (fence-ordered; DS in-order per wave).
    const int cmod = (ll < 4) ? (16 + ll) : (ll - 4);
    char* cw0 = ldsw + lq * 320 + ll * 4;
    char* cw1 = ldsw + lq * 320 + cmod * 4;
    const char* crb = ldsw + lane * 80;

    // B fragments: loaded once, reused all 19 steps.
    uint4 Bh[2][2], Bz[2][2];
    #pragma unroll
    for (int u = 0; u < 2; ++u)
        #pragma unroll
        for (int kk = 0; kk < 2; ++kk) {
            Bh[u][kk] = *(const uint4*)(ws + WS_BH + (size_t)((u * 2 + kk) * 64 + lane) * 16);
            Bz[u][kk] = *(const uint4*)(ws + WS_BZ + (size_t)((u * 2 + kk) * 64 + lane) * 16);
        }
    const unsigned int* W0p  = (const unsigned int*)(ws + WS_H1W0);
    const unsigned int* W1p  = (const unsigned int*)(ws + WS_H1W1);
    const unsigned int* B1p  = (const unsigned int*)(ws + WS_H1B);
    const unsigned int* ZW0p = (const unsigned int*)(ws + WS_Z1W0);
    const unsigned int* ZW1p = (const unsigned int*)(ws + WS_Z1W1);
    const unsigned int* ZB1p = (const unsigned int*)(ws + WS_Z1B);
    const float* Wz3s = (const float*)(ws + WS_WZ3);
    const float* bz3s = (const float*)(ws + WS_BZ3);

    const half2_t c001h = {(__fp16)0.01f, (__fp16)0.01f};
    const floatx4 ZC = {0.0f, 0.0f, 0.0f, 0.0f};   // persistent zero C-operand

    const int row = blockIdx.x * THREADS + t;
    const bool ok = row < nrows;
    const float2 w2 = *(const float2*)(w + 2 * (size_t)(ok ? row : 0));
    float h0 = w2.x, h1 = w2.y;
    float* orow = out + (size_t)row * (STEPS * 2);

    #pragma unroll 1
    for (int s = 0; s < STEPS; ++s) {
        floatx4 C[4][2];

        // ======== h path: L1 packed f16, split staging (k0..31 then k32..63) ====
        {
            const __fp16 h0h = (__fp16)h0, h1h = (__fp16)h1;
            const half2_t h00 = {h0h, h0h};
            const half2_t h11 = {h1h, h1h};
            // ---- kf0: chunks c=0..3 (k 0..31) ----
            #pragma unroll
            for (int c = 0; c < 4; ++c) {
                unsigned int dw[4];
                #pragma unroll
                for (int p = 0; p < 4; ++p) {
                    const int q = c * 4 + p;         // pair q -> k=2q,2q+1
                    half2_t v = h11 * bits2h(W1p[q]) + (h00 * bits2h(W0p[q]) + bits2h(B1p[q]));
                    v = __builtin_elementwise_max(v, v * c001h);   // packed lrelu
                    dw[p] = h2bits(v);
                }
                *(uint4*)(awb + c * 256) = make_uint4(dw[0], dw[1], dw[2], dw[3]);
            }
            LDS_FENCE();
            #pragma unroll
            for (int mt = 0; mt < 4; ++mt) {
                const half8 A0 = __builtin_bit_cast(half8, *(const uint4*)(arb + mt * 1024));
                C[mt][0] = __builtin_amdgcn_mfma_f32_16x16x32_f16(A0, __builtin_bit_cast(half8, Bh[0][0]), ZC, 0, 0, 0);
                C[mt][1] = __builtin_amdgcn_mfma_f32_16x16x32_f16(A0, __builtin_bit_cast(half8, Bh[1][0]), ZC, 0, 0, 0);
            }
            LDS_FENCE();
            // ---- kf1: chunks c=4,5 (k 32..47), chunk6 (k48,49 + bias), zeros ----
            #pragma unroll
            for (int c = 4; c < 6; ++c) {
                unsigned int dw[4];
                #pragma unroll
                for (int p = 0; p < 4; ++p) {
                    const int q = c * 4 + p;
                    half2_t v = h11 * bits2h(W1p[q]) + (h00 * bits2h(W0p[q]) + bits2h(B1p[q]));
                    v = __builtin_elementwise_max(v, v * c001h);
                    dw[p] = h2bits(v);
                }
                *(uint4*)(awb + (c - 4) * 256) = make_uint4(dw[0], dw[1], dw[2], dw[3]);
            }
            {
                half2_t v = h11 * bits2h(W1p[24]) + (h00 * bits2h(W0p[24]) + bits2h(B1p[24]));
                v = __builtin_elementwise_max(v, v * c001h);
                *(uint4*)(awb + 2 * 256) = make_uint4(h2bits(v), 0x00003C00u, 0u, 0u);
            }
            *(uint4*)(awb + 3 * 256) = make_uint4(0u, 0u, 0u, 0u);
            LDS_FENCE();
            #pragma unroll
            for (int mt = 0; mt < 4; ++mt) {
                const half8 A1 = __builtin_bit_cast(half8, *(const uint4*)(arb + mt * 1024));
                C[mt][0] = __builtin_amdgcn_mfma_f32_16x16x32_f16(A1, __builtin_bit_cast(half8, Bh[0][1]), C[mt][0], 0, 0, 0);
                C[mt][1] = __builtin_amdgcn_mfma_f32_16x16x32_f16(A1, __builtin_bit_cast(half8, Bh[1][1]), C[mt][1], 0, 0, 0);
            }
        }
        LDS_FENCE();
        #pragma unroll
        for (int mt = 0; mt < 4; ++mt)
            #pragma unroll
            for (int i = 0; i < 4; ++i)
                *(float*)(cw1 + mt * 1280 + i * 80) = C[mt][1][i];   // garbage lanes wrap
        LDS_FENCE();
        #pragma unroll
        for (int mt = 0; mt < 4; ++mt)
            #pragma unroll
            for (int i = 0; i < 4; ++i)
                *(float*)(cw0 + mt * 1280 + i * 80) = C[mt][0][i];   // real cols 0..15 win
        LDS_FENCE();
        float a2[20];
        #pragma unroll
        for (int p = 0; p < 5; ++p) {
            const float4 v = *(const float4*)(crb + p * 16);
            a2[4 * p] = v.x; a2[4 * p + 1] = v.y; a2[4 * p + 2] = v.z; a2[4 * p + 3] = v.w;
        }
        LDS_FENCE();
        float nh0 = bh3[0], nh1 = bh3[1];
        #pragma unroll
        for (int i = 0; i < 20; ++i) {
            const float a = lrelu(a2[i]);
            nh0 = fmaf(a, Wh3[2 * i], nh0);
            nh1 = fmaf(a, Wh3[2 * i + 1], nh1);
        }
        h0 = lrelu(nh0); h1 = lrelu(nh1);

        // ======== z path: L1 packed f16 incl. f16 sigmoid, split staging ========
        {
            const __fp16 g0h = (__fp16)h0, g1h = (__fp16)h1;
            const half2_t g00 = {g0h, g0h};
            const half2_t g11 = {g1h, g1h};
            #pragma unroll
            for (int c = 0; c < 4; ++c) {
                unsigned int dw[4];
                #pragma unroll
                for (int p = 0; p < 4; ++p) {
                    const int q = c * 4 + p;
                    half2_t y = g11 * bits2h(ZW1p[q]) + (g00 * bits2h(ZW0p[q]) + bits2h(ZB1p[q]));
                    dw[p] = h2bits(sigm_h2(y));
                }
                *(uint4*)(awb + c * 256) = make_uint4(dw[0], dw[1], dw[2], dw[3]);
            }
            LDS_FENCE();
            #pragma unroll
            for (int mt = 0; mt < 4; ++mt) {
                const half8 A0 = __builtin_bit_cast(half8, *(const uint4*)(arb + mt * 1024));
                C[mt][0] = __builtin_amdgcn_mfma_f32_16x16x32_f16(A0, __builtin_bit_cast(half8, Bz[0][0]), ZC, 0, 0, 0);
                C[mt][1] = __builtin_amdgcn_mfma_f32_16x16x32_f16(A0, __builtin_bit_cast(half8, Bz[1][0]), ZC, 0, 0, 0);
            }
            LDS_FENCE();
            #pragma unroll
            for (int c = 4; c < 6; ++c) {
                unsigned int dw[4];
                #pragma unroll
                for (int p = 0; p < 4; ++p) {
                    const int q = c * 4 + p;
                    half2_t y = g11 * bits2h(ZW1p[q]) + (g00 * bits2h(ZW0p[q]) + bits2h(ZB1p[q]));
                    dw[p] = h2bits(sigm_h2(y));
                }
                *(uint4*)(awb + (c - 4) * 256) = make_uint4(dw[0], dw[1], dw[2], dw[3]);
            }
            {
                half2_t y = g11 * bits2h(ZW1p[24]) + (g00 * bits2h(ZW0p[24]) + bits2h(ZB1p[24]));
                *(uint4*)(awb + 2 * 256) = make_uint4(h2bits(sigm_h2(y)), 0x00003C00u, 0u, 0u);
            }
            *(uint4*)(awb + 3 * 256) = make_uint4(0u, 0u, 0u, 0u);
            LDS_FENCE();
            #pragma unroll
            for (int mt = 0; mt < 4; ++mt) {
                const half8 A1 = __builtin_bit_cast(half8, *(const uint4*)(arb + mt * 1024));
                C[mt][0] = __builtin_amdgcn_mfma_f32_16x16x32_f16(A1, __builtin_bit_cast(half8, Bz[0][1]), C[mt][0], 0, 0, 0);
                C[mt][1] = __builtin_amdgcn_mfma_f32_16x16x32_f16(A1, __builtin_bit_cast(half8, Bz[1][1]), C[mt][1], 0, 0, 0);
            }
        }
        LDS_FENCE();
        #pragma unroll
        for (int mt = 0; mt < 4; ++mt)
            #pragma unroll
            for (int i = 0; i < 4; ++i)
                *(float*)(cw1 + mt * 1280 + i * 80) = C[mt][1][i];
        LDS_FENCE();
        #pragma unroll
        for (int mt = 0; mt < 4; ++mt)
            #pragma unroll
            for (int i = 0; i < 4; ++i)
                *(float*)(cw0 + mt * 1280 + i * 80) = C[mt][0][i];
        LDS_FENCE();
        #pragma unroll
        for (int p = 0; p < 5; ++p) {
            const float4 v = *(const float4*)(crb + p * 16);
            a2[4 * p] = v.x; a2[4 * p + 1] = v.y; a2[4 * p + 2] = v.z; a2[4 * p + 3] = v.w;
        }
        LDS_FENCE();
        float zo0 = bz3s[0], zo1 = bz3s[1];
        #pragma unroll
        for (int i = 0; i < 20; ++i) {
            const float zz = sigm2(a2[i]);
            zo0 = fmaf(zz, Wz3s[2 * i], zo0);
            zo1 = fmaf(zz, Wz3s[2 * i + 1], zo1);
        }
        if (ok) {
            float2 o; o.x = sigm2(zo0); o.y = sigm2(zo1);
            *(float2*)(orow + 2 * s) = o;
        }
    }
}

extern "C" void kernel_launch(void* const* d_in, const int* in_sizes, int n_in,
                              void* d_out, int out_size, void* d_ws, size_t ws_size,
                              hipStream_t stream) {
    const float* w   = (const float*)d_in[0];
    const float* Wh1 = (const float*)d_in[1];
    const float* bh1 = (const float*)d_in[2];
    const float* Wh2 = (const float*)d_in[3];
    const float* bh2 = (const float*)d_in[4];
    const float* Wh3 = (const float*)d_in[5];
    const float* bh3 = (const float*)d_in[6];
    const float* Wz1 = (const float*)d_in[7];
    const float* bz1 = (const float*)d_in[8];
    const float* Wz2 = (const float*)d_in[9];
    const float* bz2 = (const float*)d_in[10];
    const float* Wz3 = (const float*)d_in[11];
    const float* bz3 = (const float*)d_in[12];
    float* out = (float*)d_out;

    pack_kernel<<<1, 256, 0, stream>>>(Wh1, bh1, Wh2, bh2, Wz1, bz1, Wz2, bz2,
                                       Wz3, bz3, (char*)d_ws);

    const int nrows = in_sizes[0] / 2;  // w is [B,2]
    const int blocks = (nrows + THREADS - 1) / THREADS;
    recurrent_kernel<<<blocks, THREADS, 0, stream>>>(
        w, Wh3, bh3, (const char*)d_ws, out, nrows);
}

// Round 14
// 635.760 us; speedup vs baseline: 1.6693x; 1.6693x over previous
//
#include <hip/hip_runtime.h>
#include <math.h>

#define STEPS 19
#define THREADS 256
#define L2E 1.44269504088896340736f   // log2(e)

typedef _Float16 half8   __attribute__((ext_vector_type(8)));   // MFMA A/B frag
typedef float    floatx4 __attribute__((ext_vector_type(4)));   // MFMA C/D frag
typedef __fp16   half2_t __attribute__((ext_vector_type(2)));   // packed f16 pair

// Per-wave LDS region: A-staging uses first 4096 B (ONE 32-k half at a time,
// overwritten between MFMA halves); C-stage (5120 B, stride 20 dwords) overlays.
#define WAVE_LDS 5120

// d_ws byte offsets
#define WS_BH    0      // h-layer2 B-frags  [u][kk][lane]*16B = 4096
#define WS_BZ    4096   // z-layer2 B-frags (pre-scaled by -log2e) = 4096
#define WS_H1W0  8192   // 25 half2: {Wh1[0][2q],Wh1[0][2q+1]}
#define WS_H1W1  8292   // 25 half2: row 1
#define WS_H1B   8392   // 25 half2: bh1 pairs
#define WS_Z1W0  8492   // 25 half2: -L2E*Wz1 row 0 pairs
#define WS_Z1W1  8592   // 25 half2: -L2E*Wz1 row 1 pairs
#define WS_Z1B   8692   // 25 half2: -L2E*bz1 pairs
#define WS_WZ3   8792   // 40  f32: -L2E*Wz3
#define WS_BZ3   8952   // 2   f32: -L2E*bz3

#define LDS_FENCE() asm volatile("" ::: "memory")

__device__ __forceinline__ float lrelu(float x) { return fmaxf(x, 0.01f * x); }
__device__ __forceinline__ float sigm2(float y) {   // sigmoid, -log2e pre-folded
    return __builtin_amdgcn_rcpf(1.0f + __builtin_amdgcn_exp2f(y));
}
__device__ __forceinline__ unsigned int pkrtz_u(float a, float b) {
    return __builtin_bit_cast(unsigned int, __builtin_amdgcn_cvt_pkrtz(a, b));
}
__device__ __forceinline__ unsigned int packh2(float a, float b) {
    half2_t h; h.x = (__fp16)a; h.y = (__fp16)b;
    return __builtin_bit_cast(unsigned int, h);
}
__device__ __forceinline__ unsigned int h2bits(half2_t h) {
    return __builtin_bit_cast(unsigned int, h);
}
__device__ __forceinline__ half2_t bits2h(unsigned int u) {
    return __builtin_bit_cast(half2_t, u);
}

// packed-f16 sigmoid of a pre-scaled pair: y = -log2e*x; out = 1/(1+2^y)
__device__ __forceinline__ half2_t sigm_h2(half2_t y) {
#if __has_builtin(__builtin_elementwise_exp2) && __has_builtin(__builtin_amdgcn_rcph)
    half2_t e = __builtin_elementwise_exp2(y);            // 2x v_exp_f16
    e = e + (half2_t){(__fp16)1.0f, (__fp16)1.0f};        // v_pk_add_f16
    half2_t r;
    r.x = __builtin_amdgcn_rcph(e.x);                     // v_rcp_f16
    r.y = __builtin_amdgcn_rcph(e.y);
    return r;
#else
    return bits2h(pkrtz_u(sigm2((float)y.x), sigm2((float)y.y)));
#endif
}

// --- pack kernel ---
__global__ __launch_bounds__(256) void pack_kernel(
    const float* __restrict__ Wh1, const float* __restrict__ bh1,
    const float* __restrict__ Wh2, const float* __restrict__ bh2,
    const float* __restrict__ Wz1, const float* __restrict__ bz1,
    const float* __restrict__ Wz2, const float* __restrict__ bz2,
    const float* __restrict__ Wz3, const float* __restrict__ bz3,
    char* __restrict__ ws)
{
    const int t = threadIdx.x;
    // B-frags (16x16x32 f16): lane holds B[k=(lane>>4)*8+j][n=lane&15], j=0..7.
    // Bias row at k==50 (A supplies 1.0); k>50 rows ZERO (annihilate A pad).
    for (int e = t; e < 512; e += 256) {
        const int layer = e >> 8, r = e & 255;
        const int u = r >> 7, kk = (r >> 6) & 1, lane = r & 63;
        const int n = u * 16 + (lane & 15);
        const float* W2 = layer ? Wz2 : Wh2;
        const float* b2 = layer ? bz2 : bh2;
        const float scale = layer ? -L2E : 1.0f;
        unsigned int dw[4];
        #pragma unroll
        for (int d = 0; d < 4; ++d) {
            float v[2];
            #pragma unroll
            for (int h = 0; h < 2; ++h) {
                const int k = kk * 32 + ((lane >> 4) & 3) * 8 + 2 * d + h;
                float x = 0.0f;
                if (n < 20) {
                    if (k < 50)       x = W2[k * 20 + n] * scale;
                    else if (k == 50) x = b2[n] * scale;
                }
                v[h] = x;
            }
            dw[d] = packh2(v[0], v[1]);
        }
        *(uint4*)(ws + (layer ? WS_BZ : WS_BH) + (size_t)((u * 2 + kk) * 64 + lane) * 16)
            = make_uint4(dw[0], dw[1], dw[2], dw[3]);
    }
    if (t < 25) {
        ((unsigned int*)(ws + WS_H1W0))[t] = packh2(Wh1[2 * t],      Wh1[2 * t + 1]);
        ((unsigned int*)(ws + WS_H1W1))[t] = packh2(Wh1[50 + 2 * t], Wh1[51 + 2 * t]);
        ((unsigned int*)(ws + WS_H1B))[t]  = packh2(bh1[2 * t],      bh1[2 * t + 1]);
        ((unsigned int*)(ws + WS_Z1W0))[t] = packh2(-L2E * Wz1[2 * t],      -L2E * Wz1[2 * t + 1]);
        ((unsigned int*)(ws + WS_Z1W1))[t] = packh2(-L2E * Wz1[50 + 2 * t], -L2E * Wz1[51 + 2 * t]);
        ((unsigned int*)(ws + WS_Z1B))[t]  = packh2(-L2E * bz1[2 * t],      -L2E * bz1[2 * t + 1]);
    }
    if (t < 40)  ((float*)(ws + WS_WZ3))[t] = -L2E * Wz3[t];
    if (t < 2)   ((float*)(ws + WS_BZ3))[t] = -L2E * bz3[t];
}

__global__ __launch_bounds__(THREADS)
__attribute__((amdgpu_waves_per_eu(4)))   // budget 128 VGPR (need ~60: B-frags stay
                                          // register-resident — r13's (8)=64 forced them
                                          // to per-step global reloads, +2.2GB FETCH).
                                          // VGPR~60 allows 8 waves/EU; LDS 20480 -> 8 blk/CU
void recurrent_kernel(
    const float* __restrict__ w,
    const float* __restrict__ Wh3, const float* __restrict__ bh3,
    const char* __restrict__ ws,
    float* __restrict__ out, int nrows)
{
    __shared__ __align__(16) char lds[4 * WAVE_LDS];
    const int t    = threadIdx.x;
    const int lane = t & 63;
    const int wid  = t >> 6;
    const int lq   = (lane >> 4) & 3;
    const int ll   = lane & 15;
    char* ldsw = lds + wid * WAVE_LDS;

    // A-frag staging (ONE 32-k half at a time; conflict-free, r10-analyzed).
    char* awb = ldsw + (lane >> 4) * 1024 + (lane & 15) * 16;
    const char* arb = ldsw + lane * 16;
    // C-stage (overlays A region): row stride 20 dwords; u=1 invalid lanes wrap and
    // are overwritten by later u=0 writes (fence-ordered; DS in-order per wave).
    const int cmod = (ll < 4) ? (16 + ll) : (ll - 4);
    char* cw0 = ldsw + lq * 320 + ll * 4;
    char* cw1 = ldsw + lq * 320 + cmod * 4;
    const char* crb = ldsw + lane * 80;

    // B fragments: loaded once, reused all 19 steps.
    uint4 Bh[2][2], Bz[2][2];
    #pragma unroll
    for (int u = 0; u < 2; ++u)
        #pragma unroll
        for (int kk = 0; kk < 2; ++kk) {
            Bh[u][kk] = *(const uint4*)(ws + WS_BH + (size_t)((u * 2 + kk) * 64 + lane) * 16);
            Bz[u][kk] = *(const uint4*)(ws + WS_BZ + (size_t)((u * 2 + kk) * 64 + lane) * 16);
        }
    const unsigned int* W0p  = (const unsigned int*)(ws + WS_H1W0);
    const unsigned int* W1p  = (const unsigned int*)(ws + WS_H1W1);
    const unsigned int* B1p  = (const unsigned int*)(ws + WS_H1B);
    const unsigned int* ZW0p = (const unsigned int*)(ws + WS_Z1W0);
    const unsigned int* ZW1p = (const unsigned int*)(ws + WS_Z1W1);
    const unsigned int* ZB1p = (const unsigned int*)(ws + WS_Z1B);
    const float* Wz3s = (const float*)(ws + WS_WZ3);
    const float* bz3s = (const float*)(ws + WS_BZ3);

    const half2_t c001h = {(__fp16)0.01f, (__fp16)0.01f};
    const floatx4 ZC = {0.0f, 0.0f, 0.0f, 0.0f};   // persistent zero C-operand

    const int row = blockIdx.x * THREADS + t;
    const bool ok = row < nrows;
    const float2 w2 = *(const float2*)(w + 2 * (size_t)(ok ? row : 0));
    float h0 = w2.x, h1 = w2.y;
    float* orow = out + (size_t)row * (STEPS * 2);

    #pragma unroll 1
    for (int s = 0; s < STEPS; ++s) {
        floatx4 C[4][2];

        // ======== h path: L1 packed f16, split staging (k0..31 then k32..63) ====
        {
            const __fp16 h0h = (__fp16)h0, h1h = (__fp16)h1;
            const half2_t h00 = {h0h, h0h};
            const half2_t h11 = {h1h, h1h};
            // ---- kf0: chunks c=0..3 (k 0..31) ----
            #pragma unroll
            for (int c = 0; c < 4; ++c) {
                unsigned int dw[4];
                #pragma unroll
                for (int p = 0; p < 4; ++p) {
                    const int q = c * 4 + p;         // pair q -> k=2q,2q+1
                    half2_t v = h11 * bits2h(W1p[q]) + (h00 * bits2h(W0p[q]) + bits2h(B1p[q]));
                    v = __builtin_elementwise_max(v, v * c001h);   // packed lrelu
                    dw[p] = h2bits(v);
                }
                *(uint4*)(awb + c * 256) = make_uint4(dw[0], dw[1], dw[2], dw[3]);
            }
            LDS_FENCE();
            #pragma unroll
            for (int mt = 0; mt < 4; ++mt) {
                const half8 A0 = __builtin_bit_cast(half8, *(const uint4*)(arb + mt * 1024));
                C[mt][0] = __builtin_amdgcn_mfma_f32_16x16x32_f16(A0, __builtin_bit_cast(half8, Bh[0][0]), ZC, 0, 0, 0);
                C[mt][1] = __builtin_amdgcn_mfma_f32_16x16x32_f16(A0, __builtin_bit_cast(half8, Bh[1][0]), ZC, 0, 0, 0);
            }
            LDS_FENCE();
            // ---- kf1: chunks c=4,5 (k 32..47), chunk6 (k48,49 + bias), zeros ----
            #pragma unroll
            for (int c = 4; c < 6; ++c) {
                unsigned int dw[4];
                #pragma unroll
                for (int p = 0; p < 4; ++p) {
                    const int q = c * 4 + p;
                    half2_t v = h11 * bits2h(W1p[q]) + (h00 * bits2h(W0p[q]) + bits2h(B1p[q]));
                    v = __builtin_elementwise_max(v, v * c001h);
                    dw[p] = h2bits(v);
                }
                *(uint4*)(awb + (c - 4) * 256) = make_uint4(dw[0], dw[1], dw[2], dw[3]);
            }
            {
                half2_t v = h11 * bits2h(W1p[24]) + (h00 * bits2h(W0p[24]) + bits2h(B1p[24]));
                v = __builtin_elementwise_max(v, v * c001h);
                *(uint4*)(awb + 2 * 256) = make_uint4(h2bits(v), 0x00003C00u, 0u, 0u);
            }
            *(uint4*)(awb + 3 * 256) = make_uint4(0u, 0u, 0u, 0u);
            LDS_FENCE();
            #pragma unroll
            for (int mt = 0; mt < 4; ++mt) {
                const half8 A1 = __builtin_bit_cast(half8, *(const uint4*)(arb + mt * 1024));
                C[mt][0] = __builtin_amdgcn_mfma_f32_16x16x32_f16(A1, __builtin_bit_cast(half8, Bh[0][1]), C[mt][0], 0, 0, 0);
                C[mt][1] = __builtin_amdgcn_mfma_f32_16x16x32_f16(A1, __builtin_bit_cast(half8, Bh[1][1]), C[mt][1], 0, 0, 0);
            }
        }
        LDS_FENCE();
        #pragma unroll
        for (int mt = 0; mt < 4; ++mt)
            #pragma unroll
            for (int i = 0; i < 4; ++i)
                *(float*)(cw1 + mt * 1280 + i * 80) = C[mt][1][i];   // garbage lanes wrap
        LDS_FENCE();
        #pragma unroll
        for (int mt = 0; mt < 4; ++mt)
            #pragma unroll
            for (int i = 0; i < 4; ++i)
                *(float*)(cw0 + mt * 1280 + i * 80) = C[mt][0][i];   // real cols 0..15 win
        LDS_FENCE();
        float a2[20];
        #pragma unroll
        for (int p = 0; p < 5; ++p) {
            const float4 v = *(const float4*)(crb + p * 16);
            a2[4 * p] = v.x; a2[4 * p + 1] = v.y; a2[4 * p + 2] = v.z; a2[4 * p + 3] = v.w;
        }
        LDS_FENCE();
        float nh0 = bh3[0], nh1 = bh3[1];
        #pragma unroll
        for (int i = 0; i < 20; ++i) {
            const float a = lrelu(a2[i]);
            nh0 = fmaf(a, Wh3[2 * i], nh0);
            nh1 = fmaf(a, Wh3[2 * i + 1], nh1);
        }
        h0 = lrelu(nh0); h1 = lrelu(nh1);

        // ======== z path: L1 packed f16 incl. f16 sigmoid, split staging ========
        {
            const __fp16 g0h = (__fp16)h0, g1h = (__fp16)h1;
            const half2_t g00 = {g0h, g0h};
            const half2_t g11 = {g1h, g1h};
            #pragma unroll
            for (int c = 0; c < 4; ++c) {
                unsigned int dw[4];
                #pragma unroll
                for (int p = 0; p < 4; ++p) {
                    const int q = c * 4 + p;
                    half2_t y = g11 * bits2h(ZW1p[q]) + (g00 * bits2h(ZW0p[q]) + bits2h(ZB1p[q]));
                    dw[p] = h2bits(sigm_h2(y));
                }
                *(uint4*)(awb + c * 256) = make_uint4(dw[0], dw[1], dw[2], dw[3]);
            }
            LDS_FENCE();
            #pragma unroll
            for (int mt = 0; mt < 4; ++mt) {
                const half8 A0 = __builtin_bit_cast(half8, *(const uint4*)(arb + mt * 1024));
                C[mt][0] = __builtin_amdgcn_mfma_f32_16x16x32_f16(A0, __builtin_bit_cast(half8, Bz[0][0]), ZC, 0, 0, 0);
                C[mt][1] = __builtin_amdgcn_mfma_f32_16x16x32_f16(A0, __builtin_bit_cast(half8, Bz[1][0]), ZC, 0, 0, 0);
            }
            LDS_FENCE();
            #pragma unroll
            for (int c = 4; c < 6; ++c) {
                unsigned int dw[4];
                #pragma unroll
                for (int p = 0; p < 4; ++p) {
                    const int q = c * 4 + p;
                    half2_t y = g11 * bits2h(ZW1p[q]) + (g00 * bits2h(ZW0p[q]) + bits2h(ZB1p[q]));
                    dw[p] = h2bits(sigm_h2(y));
                }
                *(uint4*)(awb + (c - 4) * 256) = make_uint4(dw[0], dw[1], dw[2], dw[3]);
            }
            {
                half2_t y = g11 * bits2h(ZW1p[24]) + (g00 * bits2h(ZW0p[24]) + bits2h(ZB1p[24]));
                *(uint4*)(awb + 2 * 256) = make_uint4(h2bits(sigm_h2(y)), 0x00003C00u, 0u, 0u);
            }
            *(uint4*)(awb + 3 * 256) = make_uint4(0u, 0u, 0u, 0u);
            LDS_FENCE();
            #pragma unroll
            for (int mt = 0; mt < 4; ++mt) {
                const half8 A1 = __builtin_bit_cast(half8, *(const uint4*)(arb + mt * 1024));
                C[mt][0] = __builtin_amdgcn_mfma_f32_16x16x32_f16(A1, __builtin_bit_cast(half8, Bz[0][1]), C[mt][0], 0, 0, 0);
                C[mt][1] = __builtin_amdgcn_mfma_f32_16x16x32_f16(A1, __builtin_bit_cast(half8, Bz[1][1]), C[mt][1], 0, 0, 0);
            }
        }
        LDS_FENCE();
        #pragma unroll
        for (int mt = 0; mt < 4; ++mt)
            #pragma unroll
            for (int i = 0; i < 4; ++i)
                *(float*)(cw1 + mt * 1280 + i * 80) = C[mt][1][i];
        LDS_FENCE();
        #pragma unroll
        for (int mt = 0; mt < 4; ++mt)
            #pragma unroll
            for (int i = 0; i < 4; ++i)
                *(float*)(cw0 + mt * 1280 + i * 80) = C[mt][0][i];
        LDS_FENCE();
        #pragma unroll
        for (int p = 0; p < 5; ++p) {
            const float4 v = *(const float4*)(crb + p * 16);
            a2[4 * p] = v.x; a2[4 * p + 1] = v.y; a2[4 * p + 2] = v.z; a2[4 * p + 3] = v.w;
        }
        LDS_FENCE();
        float zo0 = bz3s[0], zo1 = bz3s[1];
        #pragma unroll
        for (int i = 0; i < 20; ++i) {
            const float zz = sigm2(a2[i]);
            zo0 = fmaf(zz, Wz3s[2 * i], zo0);
            zo1 = fmaf(zz, Wz3s[2 * i + 1], zo1);
        }
        if (ok) {
            float2 o; o.x = sigm2(zo0); o.y = sigm2(zo1);
            *(float2*)(orow + 2 * s) = o;
        }
    }
}

extern "C" void kernel_launch(void* const* d_in, const int* in_sizes, int n_in,
                              void* d_out, int out_size, void* d_ws, size_t ws_size,
                              hipStream_t stream) {
    const float* w   = (const float*)d_in[0];
    const float* Wh1 = (const float*)d_in[1];
    const float* bh1 = (const float*)d_in[2];
    const float* Wh2 = (const float*)d_in[3];
    const float* bh2 = (const float*)d_in[4];
    const float* Wh3 = (const float*)d_in[5];
    const float* bh3 = (const float*)d_in[6];
    const float* Wz1 = (const float*)d_in[7];
    const float* bz1 = (const float*)d_in[8];
    const float* Wz2 = (const float*)d_in[9];
    const float* bz2 = (const float*)d_in[10];
    const float* Wz3 = (const float*)d_in[11];
    const float* bz3 = (const float*)d_in[12];
    float* out = (float*)d_out;

    pack_kernel<<<1, 256, 0, stream>>>(Wh1, bh1, Wh2, bh2, Wz1, bz1, Wz2, bz2,
                                       Wz3, bz3, (char*)d_ws);

    const int nrows = in_sizes[0] / 2;  // w is [B,2]
    const int blocks = (nrows + THREADS - 1) / THREADS;
    recurrent_kernel<<<blocks, THREADS, 0, stream>>>(
        w, Wh3, bh3, (const char*)d_ws, out, nrows);
}